// Round 1
// baseline (1629.225 us; speedup 1.0000x reference)
//
#include <hip/hip_runtime.h>

// Problem constants (from reference):
//   input: (8192, 8, 128) fp32 ; cache: (262144, 8, 128) fp32
//   slot_mapping: (8192,) int32, unique
//   out = cache with out[slot_mapping[t]] = input[t]
#define NUM_TOKENS 8192
#define NUM_SLOTS  262144
#define ROW_FLOATS 1024          // 8 heads * 128 dim, contiguous per row
#define ROW_F4     (ROW_FLOATS / 4)   // 256 float4 per row

// ---------- invmap (fused) path ----------

// d_ws is poisoned to 0xAA each call; init inv[] to -1 ourselves.
__global__ void init_invmap(int* __restrict__ inv) {
    int i = blockIdx.x * blockDim.x + threadIdx.x;   // grid sized exactly NUM_SLOTS
    inv[i] = -1;
}

__global__ void build_invmap(const int* __restrict__ slot_mapping,
                             int* __restrict__ inv) {
    int t = blockIdx.x * blockDim.x + threadIdx.x;
    if (t < NUM_TOKENS) inv[slot_mapping[t]] = t;    // unique indices guaranteed
}

// One block per output row. 256 threads * float4 = 4 KiB row.
// inv[row] is wave-uniform -> scalar load + broadcast; each row is read once
// (from input if updated, else cache) and written exactly once.
__global__ __launch_bounds__(256) void write_rows(
        const float4* __restrict__ input,
        const float4* __restrict__ cache,
        const int*    __restrict__ inv,
        float4*       __restrict__ out) {
    const int row = blockIdx.x;
    const int t   = inv[row];
    const float4* src = (t >= 0)
        ? input + (size_t)t   * ROW_F4
        : cache + (size_t)row * ROW_F4;
    out[(size_t)row * ROW_F4 + threadIdx.x] = src[threadIdx.x];
}

// ---------- fallback (no workspace) path ----------

__global__ void copy_all(const float4* __restrict__ cache,
                         float4* __restrict__ out, size_t n4) {
    size_t i = (size_t)blockIdx.x * blockDim.x + threadIdx.x;
    const size_t stride = (size_t)gridDim.x * blockDim.x;
    for (; i < n4; i += stride) out[i] = cache[i];
}

__global__ __launch_bounds__(256) void scatter_rows(
        const float4* __restrict__ input,
        const int*    __restrict__ slot_mapping,
        float4*       __restrict__ out) {
    const int t    = blockIdx.x;            // one block per token
    const int slot = slot_mapping[t];       // wave-uniform scalar load
    out[(size_t)slot * ROW_F4 + threadIdx.x] =
        input[(size_t)t * ROW_F4 + threadIdx.x];
}

extern "C" void kernel_launch(void* const* d_in, const int* in_sizes, int n_in,
                              void* d_out, int out_size, void* d_ws, size_t ws_size,
                              hipStream_t stream) {
    const float4* input        = (const float4*)d_in[0];
    const float4* cache        = (const float4*)d_in[1];
    const int*    slot_mapping = (const int*)d_in[2];
    float4*       out          = (float4*)d_out;

    if (ws_size >= (size_t)NUM_SLOTS * sizeof(int)) {
        int* inv = (int*)d_ws;
        init_invmap<<<NUM_SLOTS / 256, 256, 0, stream>>>(inv);
        build_invmap<<<(NUM_TOKENS + 255) / 256, 256, 0, stream>>>(slot_mapping, inv);
        write_rows<<<NUM_SLOTS, 256, 0, stream>>>(input, cache, inv, out);
    } else {
        const size_t n4 = (size_t)NUM_SLOTS * ROW_F4;
        copy_all<<<4096, 256, 0, stream>>>(cache, out, n4);
        scatter_rows<<<NUM_TOKENS, 256, 0, stream>>>(input, slot_mapping, out);
    }
}